// Round 14
// baseline (144.683 us; speedup 1.0000x reference)
//
#include <hip/hip_runtime.h>

// out[m,n] = max_k min(x[m,k], w[k,n])  — tropical matmul, M=1024 K=512 N=512 fp32.
//
// R14 = PROBE of the R13 f16 main loop (reps=8, runtime arg).
// R13 evidence: f16 main ~28us L2-WARM (converter pre-warms) vs 4.4us issue
// model — a ~5x gap never directly measured on the current kernel shape.
// reps-loop re-traverses k with a rep-dependent rotation (rep*16+i)&31 so
// the compiler cannot hoist the w loads; max is idempotent -> same output.
// The 8x kernel re-enters top-5 -> VALUBusy/VGPR/FETCH for THIS loop.
//   Branch A (per-rep structural): dur ~240-270; VALUBusy>70% = instr bloat
//     (pk lowering / AGPR shuffle), VALUBusy<40% = warm-latency exposure.
//   Branch B (fixed cost outside loop): dur ~110-130.

typedef _Float16 h2 __attribute__((ext_vector_type(2)));
typedef unsigned int uint32;

#define MDIM 1024
#define KDIM 512
#define NDIM 512
#define K2   (KDIM / 2)    // 256 k-pairs
#define MB   8             // m-rows per block tile
#define NT   256           // n-cols per block tile (4 per lane)
#define NWAVE 8
#define KP   (K2 / NWAVE)  // 32 k-pairs per wave

__device__ __forceinline__ h2 h2min(h2 a, h2 b) { return __builtin_elementwise_min(a, b); }
__device__ __forceinline__ h2 h2max(h2 a, h2 b) { return __builtin_elementwise_max(a, b); }

// --- converter: fp32 x,w -> packed-k half2 xp,wp (also pre-warms L2) ---
__global__ __launch_bounds__(512) void pack_f16(const float* __restrict__ x,
                                                const float* __restrict__ w,
                                                uint32* __restrict__ xp,
                                                uint32* __restrict__ wp)
{
    const int b = blockIdx.x, tid = threadIdx.x;
    if (b < 256) {
        const int idx = b * 512 + tid;
        const int k2 = idx >> 9, n = idx & 511;
        h2 v;
        v[0] = (_Float16)w[(size_t)(2 * k2) * NDIM + n];
        v[1] = (_Float16)w[(size_t)(2 * k2 + 1) * NDIM + n];
        wp[idx] = __builtin_bit_cast(uint32, v);
    } else {
        const int idx = (b - 256) * 512 + tid;
        const float2 f = ((const float2*)x)[idx];
        h2 v;
        v[0] = (_Float16)f.x;
        v[1] = (_Float16)f.y;
        xp[idx] = __builtin_bit_cast(uint32, v);
    }
}

// --- main: packed tropical matmul, reps-instrumented ---
__global__ __launch_bounds__(512, 2) void tropical_h16r(
    const uint32* __restrict__ xp,
    const uint32* __restrict__ wp,
    float* __restrict__ out,
    int reps)
{
    const int tid  = threadIdx.x;
    const int lane = tid & 63;
    const int wv   = tid >> 6;
    const int m0   = blockIdx.x * MB;
    const int n0   = blockIdx.y * NT;
    const int kp0  = __builtin_amdgcn_readfirstlane(wv * KP);

    __shared__ float red[NWAVE][MB][NT];

    const uint4* __restrict__ wb =
        (const uint4*)(wp + (size_t)kp0 * NDIM + n0) + lane;
    const uint32* __restrict__ xr0 = xp + (size_t)m0 * K2 + kp0;

    h2 acc[MB][4];
#pragma unroll
    for (int r = 0; r < MB; ++r)
#pragma unroll
        for (int j = 0; j < 4; ++j) acc[r][j] = (h2)0;

    for (int rep = 0; rep < reps; ++rep) {
        const int base = __builtin_amdgcn_readfirstlane((rep * 16) & (KP - 1));
#pragma unroll 4
        for (int i = 0; i < KP; ++i) {
            const int row = (base + i) & (KP - 1);   // rep-dependent rotation
            const uint4 A = wb[(size_t)row * 128];
#pragma unroll
            for (int r = 0; r < MB; ++r) {
                const h2 xv = __builtin_bit_cast(h2, xr0[(size_t)r * K2 + row]);
                acc[r][0] = h2max(acc[r][0], h2min(xv, __builtin_bit_cast(h2, A.x)));
                acc[r][1] = h2max(acc[r][1], h2min(xv, __builtin_bit_cast(h2, A.y)));
                acc[r][2] = h2max(acc[r][2], h2min(xv, __builtin_bit_cast(h2, A.z)));
                acc[r][3] = h2max(acc[r][3], h2min(xv, __builtin_bit_cast(h2, A.w)));
            }
        }
    }

    // merge packed halves -> fp32, tree-combine the 8 k-split partials
#pragma unroll
    for (int r = 0; r < MB; ++r) {
        float4 v;
        v.x = fmaxf((float)acc[r][0][0], (float)acc[r][0][1]);
        v.y = fmaxf((float)acc[r][1][0], (float)acc[r][1][1]);
        v.z = fmaxf((float)acc[r][2][0], (float)acc[r][2][1]);
        v.w = fmaxf((float)acc[r][3][0], (float)acc[r][3][1]);
        ((float4*)&red[wv][r][0])[lane] = v;
    }
    __syncthreads();

    {
        const int r  = tid >> 6;
        const int c4 = tid & 63;
        float4 v = ((const float4*)&red[0][r][0])[c4];
#pragma unroll
        for (int q = 1; q < NWAVE; ++q) {
            float4 u = ((const float4*)&red[q][r][0])[c4];
            v.x = fmaxf(v.x, u.x); v.y = fmaxf(v.y, u.y);
            v.z = fmaxf(v.z, u.z); v.w = fmaxf(v.w, u.w);
        }
        *(float4*)(out + (size_t)(m0 + r) * NDIM + n0 + 4 * c4) = v;
    }
}

extern "C" void kernel_launch(void* const* d_in, const int* in_sizes, int n_in,
                              void* d_out, int out_size, void* d_ws, size_t ws_size,
                              hipStream_t stream) {
    const float* x = (const float*)d_in[0];   // (1024, 512)
    const float* w = (const float*)d_in[1];   // (512, 512)
    float* out = (float*)d_out;               // (1024, 512)

    uint32* xp = (uint32*)d_ws;               // 1 MB
    uint32* wp = xp + (size_t)MDIM * K2;      // 0.5 MB

    pack_f16<<<dim3(768), dim3(512), 0, stream>>>(x, w, xp, wp);
    tropical_h16r<<<dim3(MDIM / MB, NDIM / NT), dim3(512), 0, stream>>>(xp, wp, out, 8);
}

// Round 15
// 72.327 us; speedup vs baseline: 2.0004x; 2.0004x over previous
//
#include <hip/hip_runtime.h>

// out[m,n] = max_k min(x[m,k], w[k,n])  — tropical matmul, M=1024 K=512 N=512 fp32.
//
// R15: LDS-resident f16 loop + async burst staging.
// R14 probe: warm traversal 9.9us (VALUBusy 73%, 27% stall from per-iter
// s_load lgkm chains) + 18us fixed (first traversal pays serialized L1-miss
// latency for the w-window). Fixes:
//  (1) w staged per-wave via global_load_lds(width16), dbuf chunks of 4 rows,
//      explicit s_waitcnt vmcnt(4): a chunk's 4 misses fly together and
//      overlap the previous chunk's compute -> cold latency amortized.
//  (2) block x-tile (8KB) staged to LDS once; per-iter x = broadcast
//      ds_read_b32 (same addr all lanes, conflict-free, LDS pipe || VALU)
//      -> no SMEM stall chain.
//  (3) inner k-pair: 1 ds_read_b128 (w) + 8 bcast ds_read (x) + 64 pk ops
//      (v_pk_min/max_f16, 1.0 instr/position). Issue floor ~4.5us.
// No barriers in the loop (per-wave LDS regions). red aliases wbuf after one
// __syncthreads. LDS total 72KB. f16 error <=4.9e-4 << 2e-2 threshold.

typedef _Float16 h2 __attribute__((ext_vector_type(2)));
typedef unsigned int uint32;

#define MDIM 1024
#define KDIM 512
#define NDIM 512
#define K2   256           // k-pairs
#define MB   8             // m-rows per block tile
#define NT   256           // n-cols per block tile (4 per lane)
#define NWAVE 8
#define KP   32            // k-pairs per wave
#define CH   4             // k-pairs per staged chunk
#define NCH  (KP / CH)     // 8 chunks

__device__ __forceinline__ h2 h2min(h2 a, h2 b) { return __builtin_elementwise_min(a, b); }
__device__ __forceinline__ h2 h2max(h2 a, h2 b) { return __builtin_elementwise_max(a, b); }

typedef const __attribute__((address_space(1))) uint32 guint;
typedef __attribute__((address_space(3))) uint32 luint;

// --- converter: fp32 x,w -> packed-k half2 xp,wp (also pre-warms L2) ---
__global__ __launch_bounds__(512) void pack_f16(const float* __restrict__ x,
                                                const float* __restrict__ w,
                                                uint32* __restrict__ xp,
                                                uint32* __restrict__ wp)
{
    const int b = blockIdx.x, tid = threadIdx.x;
    if (b < 256) {                      // wp[k2*512 + n] = (w[2k2][n], w[2k2+1][n])
        const int idx = b * 512 + tid;
        const int k2 = idx >> 9, n = idx & 511;
        h2 v;
        v[0] = (_Float16)w[(size_t)(2 * k2) * NDIM + n];
        v[1] = (_Float16)w[(size_t)(2 * k2 + 1) * NDIM + n];
        wp[idx] = __builtin_bit_cast(uint32, v);
    } else {                            // xp[m*256 + k2] = (x[m][2k2], x[m][2k2+1])
        const int idx = (b - 256) * 512 + tid;
        const float2 f = ((const float2*)x)[idx];
        h2 v;
        v[0] = (_Float16)f.x;
        v[1] = (_Float16)f.y;
        xp[idx] = __builtin_bit_cast(uint32, v);
    }
}

// --- main: packed tropical matmul, LDS-resident ---
__global__ __launch_bounds__(512, 2) void tropical_r15(
    const uint32* __restrict__ xp,
    const uint32* __restrict__ wp,
    float* __restrict__ out)
{
    const int tid  = threadIdx.x;
    const int lane = tid & 63;
    const int wv   = tid >> 6;                  // 0..7: k-slice of this wave
    const int m0   = blockIdx.x * MB;
    const int n0   = blockIdx.y * NT;
    const int kp0  = wv * KP;                   // wave's k-pair window base

    // smem: [0,2048) uints = xs (8KB block x-tile, xs[i]=xp[m0*K2+i]);
    //       [2048,18432) = per-wave w dbuf (8KB/wave); red aliases this later.
    __shared__ uint32 smem[18432];              // 72 KB
    uint32* xs    = smem;
    uint32* wbase = smem + 2048;

    // stage block x-tile: 8 rows x 256 pairs = 2048 uints, 512 x uint4
    {
        const uint4* src = (const uint4*)(xp + (size_t)m0 * K2);
        ((uint4*)xs)[tid] = src[tid];
    }
    __syncthreads();                            // xs visible to all waves

    // per-wave w staging: chunk c = 4 rows of 1KB each
    uint32* mybuf = wbase + wv * 2048;          // two 1024-uint buffers
    const uint32* __restrict__ wsrc = wp + (size_t)kp0 * NDIM + n0;

    auto stage = [&](int c) {
        uint32* dst = mybuf + (c & 1) * 1024;
        const uint32* g = wsrc + (size_t)c * CH * NDIM + lane * 4;
#pragma unroll
        for (int r = 0; r < CH; ++r)
            __builtin_amdgcn_global_load_lds((guint*)(g + (size_t)r * NDIM),
                                             (luint*)(dst + r * 256), 16, 0, 0);
    };

    h2 acc[MB][4];
#pragma unroll
    for (int r = 0; r < MB; ++r)
#pragma unroll
        for (int j = 0; j < 4; ++j) acc[r][j] = (h2)0;   // inputs >= 0

    stage(0);
    for (int c = 0; c < NCH; ++c) {
        if (c + 1 < NCH) {
            stage(c + 1);
            __builtin_amdgcn_s_waitcnt(0x0F74);  // vmcnt(4): chunk c landed
        } else {
            __builtin_amdgcn_s_waitcnt(0x0F70);  // vmcnt(0)
        }
        const uint32* lw = mybuf + (c & 1) * 1024;
        const uint32* xc = xs + kp0 + c * CH;    // row r at xc[r*256 + j]
#pragma unroll
        for (int j = 0; j < CH; ++j) {
            const uint4 A = *(const uint4*)(lw + j * 256 + lane * 4);
#pragma unroll
            for (int r = 0; r < MB; ++r) {
                const h2 xv = __builtin_bit_cast(h2, xc[r * 256 + j]);  // bcast
                acc[r][0] = h2max(acc[r][0], h2min(xv, __builtin_bit_cast(h2, A.x)));
                acc[r][1] = h2max(acc[r][1], h2min(xv, __builtin_bit_cast(h2, A.y)));
                acc[r][2] = h2max(acc[r][2], h2min(xv, __builtin_bit_cast(h2, A.z)));
                acc[r][3] = h2max(acc[r][3], h2min(xv, __builtin_bit_cast(h2, A.w)));
            }
        }
    }

    // merge packed halves -> fp32; tree-combine via red (aliases wbuf region)
    __syncthreads();                            // all waves done with wbuf
    float* red = (float*)(smem + 2048);         // red[wv][r][NT] = 64KB
#pragma unroll
    for (int r = 0; r < MB; ++r) {
        float4 v;
        v.x = fmaxf((float)acc[r][0][0], (float)acc[r][0][1]);
        v.y = fmaxf((float)acc[r][1][0], (float)acc[r][1][1]);
        v.z = fmaxf((float)acc[r][2][0], (float)acc[r][2][1]);
        v.w = fmaxf((float)acc[r][3][0], (float)acc[r][3][1]);
        ((float4*)(red + ((size_t)wv * MB + r) * NT))[lane] = v;
    }
    __syncthreads();

    {
        const int r  = tid >> 6;                // 0..7
        const int c4 = tid & 63;                // one float4 each
        float4 v = ((const float4*)(red + (size_t)r * NT))[c4];
#pragma unroll
        for (int q = 1; q < NWAVE; ++q) {
            float4 u = ((const float4*)(red + ((size_t)q * MB + r) * NT))[c4];
            v.x = fmaxf(v.x, u.x); v.y = fmaxf(v.y, u.y);
            v.z = fmaxf(v.z, u.z); v.w = fmaxf(v.w, u.w);
        }
        *(float4*)(out + (size_t)(m0 + r) * NDIM + n0 + 4 * c4) = v;
    }
}

extern "C" void kernel_launch(void* const* d_in, const int* in_sizes, int n_in,
                              void* d_out, int out_size, void* d_ws, size_t ws_size,
                              hipStream_t stream) {
    const float* x = (const float*)d_in[0];   // (1024, 512)
    const float* w = (const float*)d_in[1];   // (512, 512)
    float* out = (float*)d_out;               // (1024, 512)

    uint32* xp = (uint32*)d_ws;               // 1 MB
    uint32* wp = xp + (size_t)MDIM * K2;      // 0.5 MB

    pack_f16<<<dim3(768), dim3(512), 0, stream>>>(x, w, xp, wp);
    tropical_r15<<<dim3(MDIM / MB, NDIM / NT), dim3(512), 0, stream>>>(xp, wp, out);
}

// Round 16
// 72.140 us; speedup vs baseline: 2.0056x; 1.0026x over previous
//
#include <hip/hip_runtime.h>

// out[m,n] = max_k min(x[m,k], w[k,n])  — tropical matmul, M=1024 K=512 N=512 fp32.
//
// R16 = R13 structure with the packed ops FORCED to v_pk_min_f16/v_pk_max_f16
// via inline asm. Theory: __builtin_elementwise_min/max on _Float16x2
// scalarized to 2x v_min_f16 (never verified) -> R14's measured warm
// traversal 9.9us @ VALUBusy 73% matches 128 VALU/iter scalarized exactly
// (17.4K cy/SIMD = 7.25us busy / 9.9 = 73%). It also explains f16==fp32:
// scalarized f16 = 2.0 instr/pos vs fp32 1.78. True pk = 1.0 instr/pos.
// Single-variable A/B vs R13 (same converter, s_load x, register-dbuf w,
// LDS tree epilogue). f16 RNE error <= 4.9e-4 << 2e-2 threshold.

typedef _Float16 h2 __attribute__((ext_vector_type(2)));
typedef unsigned int uint32;

#define MDIM 1024
#define KDIM 512
#define NDIM 512
#define K2   (KDIM / 2)    // 256 k-pairs
#define MB   8             // m-rows per block tile
#define NT   256           // n-cols per block tile (4 per lane)
#define NWAVE 8
#define KP   (K2 / NWAVE)  // 32 k-pairs per wave

__device__ __forceinline__ uint32 pkmin(uint32 a, uint32 b) {
    uint32 d;
    asm("v_pk_min_f16 %0, %1, %2" : "=v"(d) : "v"(a), "v"(b));
    return d;
}
__device__ __forceinline__ uint32 pkmax(uint32 a, uint32 b) {
    uint32 d;
    asm("v_pk_max_f16 %0, %1, %2" : "=v"(d) : "v"(a), "v"(b));
    return d;
}

// --- converter: fp32 x,w -> packed-k half2 xp,wp (also pre-warms L2) ---
__global__ __launch_bounds__(512) void pack_f16(const float* __restrict__ x,
                                                const float* __restrict__ w,
                                                uint32* __restrict__ xp,
                                                uint32* __restrict__ wp)
{
    const int b = blockIdx.x, tid = threadIdx.x;
    if (b < 256) {                      // wp[k2*512 + n] = (w[2k2][n], w[2k2+1][n])
        const int idx = b * 512 + tid;
        const int k2 = idx >> 9, n = idx & 511;
        h2 v;
        v[0] = (_Float16)w[(size_t)(2 * k2) * NDIM + n];
        v[1] = (_Float16)w[(size_t)(2 * k2 + 1) * NDIM + n];
        wp[idx] = __builtin_bit_cast(uint32, v);
    } else {                            // xp[m*256 + k2] = (x[m][2k2], x[m][2k2+1])
        const int idx = (b - 256) * 512 + tid;
        const float2 f = ((const float2*)x)[idx];
        h2 v;
        v[0] = (_Float16)f.x;
        v[1] = (_Float16)f.y;
        xp[idx] = __builtin_bit_cast(uint32, v);
    }
}

// --- main: packed tropical matmul, true v_pk ops ---
__global__ __launch_bounds__(512, 2) void tropical_r16(
    const uint32* __restrict__ xp,
    const uint32* __restrict__ wp,
    float* __restrict__ out)
{
    const int tid  = threadIdx.x;
    const int lane = tid & 63;
    const int wv   = tid >> 6;                  // 0..7: k-slice of this wave
    const int m0   = blockIdx.x * MB;
    const int n0   = blockIdx.y * NT;
    const int kp0  = __builtin_amdgcn_readfirstlane(wv * KP);   // uniform window

    __shared__ float red[NWAVE][MB][NT];        // 64 KB tree-reduce buffer

    // w: row k2 at wb[k2*128]; uint4 = 4 cols (each a packed k-pair)
    const uint4* __restrict__ wb =
        (const uint4*)(wp + (size_t)kp0 * NDIM + n0) + lane;
    // x: uniform row pointers -> s_load path
    const uint32* __restrict__ xr0 = xp + (size_t)m0 * K2 + kp0;

    uint32 acc[MB][4];
#pragma unroll
    for (int r = 0; r < MB; ++r)
#pragma unroll
        for (int j = 0; j < 4; ++j) acc[r][j] = 0u;   // +0.0 pair; inputs >= 0

    uint4 A = wb[0], B = wb[(size_t)128];

#pragma unroll 2
    for (int i = 0; i < KP; ++i) {              // one packed k-pair per iter
        uint4 C;
        if (i + 2 < KP) C = wb[(size_t)(i + 2) * 128];
#pragma unroll
        for (int r = 0; r < MB; ++r) {
            const uint32 xv = xr0[(size_t)r * K2 + i];   // uniform -> SGPR
            acc[r][0] = pkmax(acc[r][0], pkmin(xv, A.x));
            acc[r][1] = pkmax(acc[r][1], pkmin(xv, A.y));
            acc[r][2] = pkmax(acc[r][2], pkmin(xv, A.z));
            acc[r][3] = pkmax(acc[r][3], pkmin(xv, A.w));
        }
        A = B; B = C;
    }

    // merge packed halves -> fp32, tree-combine the 8 k-split partials
#pragma unroll
    for (int r = 0; r < MB; ++r) {
        float4 v;
        {
            h2 a0 = __builtin_bit_cast(h2, acc[r][0]);
            h2 a1 = __builtin_bit_cast(h2, acc[r][1]);
            h2 a2 = __builtin_bit_cast(h2, acc[r][2]);
            h2 a3 = __builtin_bit_cast(h2, acc[r][3]);
            v.x = fmaxf((float)a0[0], (float)a0[1]);
            v.y = fmaxf((float)a1[0], (float)a1[1]);
            v.z = fmaxf((float)a2[0], (float)a2[1]);
            v.w = fmaxf((float)a3[0], (float)a3[1]);
        }
        ((float4*)&red[wv][r][0])[lane] = v;
    }
    __syncthreads();

    {
        const int r  = tid >> 6;                // 0..7
        const int c4 = tid & 63;                // one float4 each
        float4 v = ((const float4*)&red[0][r][0])[c4];
#pragma unroll
        for (int q = 1; q < NWAVE; ++q) {
            float4 u = ((const float4*)&red[q][r][0])[c4];
            v.x = fmaxf(v.x, u.x); v.y = fmaxf(v.y, u.y);
            v.z = fmaxf(v.z, u.z); v.w = fmaxf(v.w, u.w);
        }
        *(float4*)(out + (size_t)(m0 + r) * NDIM + n0 + 4 * c4) = v;
    }
}

extern "C" void kernel_launch(void* const* d_in, const int* in_sizes, int n_in,
                              void* d_out, int out_size, void* d_ws, size_t ws_size,
                              hipStream_t stream) {
    const float* x = (const float*)d_in[0];   // (1024, 512)
    const float* w = (const float*)d_in[1];   // (512, 512)
    float* out = (float*)d_out;               // (1024, 512)

    uint32* xp = (uint32*)d_ws;               // 1 MB
    uint32* wp = xp + (size_t)MDIM * K2;      // 0.5 MB

    pack_f16<<<dim3(768), dim3(512), 0, stream>>>(x, w, xp, wp);
    tropical_r16<<<dim3(MDIM / MB, NDIM / NT), dim3(512), 0, stream>>>(xp, wp, out);
}